// Round 4
// baseline (211.428 us; speedup 1.0000x reference)
//
#include <hip/hip_runtime.h>
#include <math.h>

#define B_  8
#define N_  128
#define T_  256
#define L_  32
#define H_  128
#define TT_ 224   // T - L

typedef float f4 __attribute__((ext_vector_type(4)));

__device__ __forceinline__ float fsig(float x) {
    return __builtin_amdgcn_rcpf(1.0f + __expf(-x));
}
__device__ __forceinline__ float ftanh_(float x) {
    return 1.0f - 2.0f * __builtin_amdgcn_rcpf(1.0f + __expf(2.0f * x));
}

// ---------------------------------------------------------------------------
// Kernel 0: Wsum[n,h] = sum_j W_fc[n,j,h]; bsum[n] = sum_j b_fc[n,j]
// ---------------------------------------------------------------------------
__global__ __launch_bounds__(512)
void k_pre(const float* __restrict__ W_fc, const float* __restrict__ b_fc,
           float* __restrict__ wsum, float* __restrict__ bsum) {
    const int n  = blockIdx.x;
    const int h  = threadIdx.x & 127;
    const int jq = threadIdx.x >> 7;          // 0..3
    const float* W = W_fc + (size_t)n * N_ * H_ + (size_t)jq * 32 * H_;
    float s = 0.f;
    #pragma unroll 8
    for (int j = 0; j < 32; ++j) s += W[j * H_ + h];
    __shared__ float part[4][128];
    __shared__ float bp[2];
    part[jq][h] = s;

    if (threadIdx.x < 128) {
        float bv = b_fc[n * N_ + threadIdx.x];
        #pragma unroll
        for (int off = 32; off > 0; off >>= 1) bv += __shfl_down(bv, off, 64);
        if ((threadIdx.x & 63) == 0) bp[threadIdx.x >> 6] = bv;
    }
    __syncthreads();
    if (threadIdx.x < 128)
        wsum[n * H_ + h] = part[0][h] + part[1][h] + part[2][h] + part[3][h];
    if (threadIdx.x == 0) bsum[n] = bp[0] + bp[1];
}

// ---------------------------------------------------------------------------
// Kernel 1: per (b,n) block.
// KEY FIX vs R1-R3: amdgpu_waves_per_eu(2,2). __launch_bounds__' 2nd arg only
// sets a VGPR *ceiling*; the scheduler still TARGETS max occupancy and at
// 80 VGPRs kept spilling/sinking the 96 weight floats (R3's per-batch asm
// pins were satisfied 32-at-a-time then spilled to scratch -> identical
// 136 us three rounds running). max waves/EU = 2 caps the scheduler's
// occupancy target, giving the allocator a ~256-VGPR budget. The single
// combined asm pin below requires all 96 weight floats in VGPRs
// simultaneously, so VGPR_Count is the tell: >=128 means it worked.
// ---------------------------------------------------------------------------
__global__ __launch_bounds__(256)
__attribute__((amdgpu_waves_per_eu(2, 2)))
void k_main(const float* __restrict__ x, const float* __restrict__ W_ih,
            const float* __restrict__ b_ih, const float* __restrict__ b_hh,
            const float* __restrict__ wsum, const float* __restrict__ bsum,
            float* __restrict__ Hd, float* __restrict__ Dinv,
            float* __restrict__ xhat) {
    const int n   = blockIdx.x;
    const int b   = blockIdx.y;
    const int tid = threadIdx.x;
    const int h    = tid & 127;
    const int tg   = tid >> 7;   // 0 or 1
    const int wid  = tid >> 6;   // 0..3
    const int lane = tid & 63;

    __shared__ float xs[T_];
    __shared__ float xr[TT_];
    __shared__ float bia[3 * H_];
    __shared__ float ws_s[H_];
    __shared__ float xh_w[4][112];
    __shared__ float hd_s[H_];
    __shared__ float red[4];

    // ---- W rows into registers, single combined asm pin ----
    const f4* Wi4 = (const f4*)(W_ih + ((size_t)n * 4 * H_ + h)          * L_);
    const f4* Wg4 = (const f4*)(W_ih + ((size_t)n * 4 * H_ + 2 * H_ + h) * L_);
    const f4* Wo4 = (const f4*)(W_ih + ((size_t)n * 4 * H_ + 3 * H_ + h) * L_);
    f4 wi[8], wg[8], wo[8];
    #pragma unroll
    for (int i = 0; i < 8; ++i) { wi[i] = Wi4[i]; wg[i] = Wg4[i]; wo[i] = Wo4[i]; }
    asm volatile("" : "+v"(wi[0]), "+v"(wi[1]), "+v"(wi[2]), "+v"(wi[3]),
                      "+v"(wi[4]), "+v"(wi[5]), "+v"(wi[6]), "+v"(wi[7]),
                      "+v"(wg[0]), "+v"(wg[1]), "+v"(wg[2]), "+v"(wg[3]),
                      "+v"(wg[4]), "+v"(wg[5]), "+v"(wg[6]), "+v"(wg[7]),
                      "+v"(wo[0]), "+v"(wo[1]), "+v"(wo[2]), "+v"(wo[3]),
                      "+v"(wo[4]), "+v"(wo[5]), "+v"(wo[6]), "+v"(wo[7]));

    // ---- stage x, biases, wsum ----
    xs[tid] = x[((size_t)b * N_ + n) * T_ + tid];
    {
        const float* bi = b_ih + (size_t)n * 4 * H_;
        const float* bh = b_hh + (size_t)n * 4 * H_;
        if (tid < 128) {
            bia[tid]       = bi[tid]       + bh[tid];        // gi
            bia[256 + tid] = bi[384 + tid] + bh[384 + tid];  // go
        } else {
            bia[tid] = bi[128 + tid] + bh[128 + tid];        // gg
            ws_s[tid - 128] = wsum[n * H_ + (tid - 128)];
        }
    }
    __syncthreads();
    if (tid < TT_) xr[tid] = 1.0f / xs[L_ + tid];
    __syncthreads();

    const float bii = bia[h], bgg = bia[128 + h], boo = bia[256 + h];
    const float wsh = ws_s[h];
    float hd_acc = 0.f;
    const int t0 = tg * 112;

    // ---- main loop: 28 groups of 4 t each; L chunked 4x8 ----
    for (int grp = 0; grp < 28; ++grp) {
        const int tb = t0 + grp * 4;           // multiple of 4 -> aligned b128
        float gi_[4] = {bii, bii, bii, bii};
        float gg_[4] = {bgg, bgg, bgg, bgg};
        float go_[4] = {boo, boo, boo, boo};
        #pragma unroll
        for (int lc = 0; lc < 4; ++lc) {
            const f4 xa = *(const f4*)&xs[tb + 8 * lc];
            const f4 xb = *(const f4*)&xs[tb + 8 * lc + 4];
            const f4 xc = *(const f4*)&xs[tb + 8 * lc + 8];
            float xw[12];
            #pragma unroll
            for (int k = 0; k < 4; ++k) {
                xw[k] = xa[k]; xw[4 + k] = xb[k]; xw[8 + k] = xc[k];
            }
            #pragma unroll
            for (int l = 0; l < 8; ++l) {
                const int la = 8 * lc + l;
                const float wI = wi[la >> 2][la & 3];
                const float wG = wg[la >> 2][la & 3];
                const float wO = wo[la >> 2][la & 3];
                #pragma unroll
                for (int dt = 0; dt < 4; ++dt) {
                    const float xl = xw[l + dt];
                    gi_[dt] = fmaf(xl, wI, gi_[dt]);
                    gg_[dt] = fmaf(xl, wG, gg_[dt]);
                    go_[dt] = fmaf(xl, wO, go_[dt]);
                }
            }
        }
        const f4 xr4 = *(const f4*)&xr[tb];
        #pragma unroll
        for (int dt = 0; dt < 4; ++dt) {
            const float c  = fsig(gi_[dt]) * ftanh_(gg_[dt]);
            const float hh = fsig(go_[dt]) * ftanh_(c);
            hd_acc = fmaf(hh, xr4[dt], hd_acc);
            float p = hh * wsh;
            #pragma unroll
            for (int off = 32; off > 0; off >>= 1) p += __shfl_down(p, off, 64);
            if (lane == 0) xh_w[wid][tb + dt - t0] = p;
        }
    }

    // ---- Hd combine ----
    if (tg == 0) hd_s[h] = hd_acc;
    __syncthreads();
    if (tg == 1) Hd[((size_t)b * N_ + n) * H_ + h] = hd_s[h] + hd_acc;

    // ---- X_hat writeout ----
    if (tid < TT_) {
        const int t = tid;
        const float v = (t < 112) ? (xh_w[0][t] + xh_w[1][t])
                                  : (xh_w[2][t - 112] + xh_w[3][t - 112]);
        xhat[((size_t)b * TT_ + t) * N_ + n] = v + bsum[n] + 1e-6f;
    }

    // ---- Dinv ----
    float dv = (tid < TT_) ? xr[tid] : 0.f;
    #pragma unroll
    for (int off = 32; off > 0; off >>= 1) dv += __shfl_down(dv, off, 64);
    if (lane == 0) red[wid] = dv;
    __syncthreads();
    if (tid == 0) Dinv[b * N_ + n] = red[0] + red[1] + red[2] + red[3];
}

// ---------------------------------------------------------------------------
// Kernel 2: G[b,j,n] = (1/224)*(sum_h W_fc[n,j,h]*Hd[b,n,h] + b_fc[n,j]*Dinv[b,n])
// ---------------------------------------------------------------------------
__global__ __launch_bounds__(256)
void k_g(const float* __restrict__ W_fc, const float* __restrict__ b_fc,
         const float* __restrict__ Hd, const float* __restrict__ Dinv,
         float* __restrict__ G) {
    const int n = blockIdx.x;
    __shared__ f4 wrow[128 * 33];          // 67.6 KB
    __shared__ float hd_s[B_][H_];
    __shared__ float dinv_s[B_];
    __shared__ float pacc[128][B_];

    const f4* Wg = (const f4*)(W_fc + (size_t)n * N_ * H_);   // 4096 f4
    for (int i = threadIdx.x; i < 4096; i += 256) {
        const int j = i >> 5, c = i & 31;
        wrow[j * 33 + c] = Wg[i];
    }
    for (int i = threadIdx.x; i < B_ * H_; i += 256)
        hd_s[i >> 7][i & 127] = Hd[((size_t)(i >> 7) * N_ + n) * H_ + (i & 127)];
    if (threadIdx.x < B_) dinv_s[threadIdx.x] = Dinv[threadIdx.x * N_ + n];
    __syncthreads();

    const int j   = threadIdx.x & 127;
    const int hh2 = threadIdx.x >> 7;   // 0 or 1 (wave-uniform)
    float acc[B_];
    #pragma unroll
    for (int bb = 0; bb < B_; ++bb) acc[bb] = 0.f;
    #pragma unroll
    for (int q = 0; q < 16; ++q) {
        const f4 w = wrow[j * 33 + hh2 * 16 + q];
        const int hb = hh2 * 64 + q * 4;
        #pragma unroll
        for (int bb = 0; bb < B_; ++bb) {
            acc[bb] = fmaf(w[0], hd_s[bb][hb + 0],
                      fmaf(w[1], hd_s[bb][hb + 1],
                      fmaf(w[2], hd_s[bb][hb + 2],
                      fmaf(w[3], hd_s[bb][hb + 3], acc[bb]))));
        }
    }
    if (hh2 == 1) {
        #pragma unroll
        for (int bb = 0; bb < B_; ++bb) pacc[j][bb] = acc[bb];
    }
    __syncthreads();
    if (hh2 == 0) {
        const float bj  = b_fc[n * N_ + j];
        const float inv = 1.0f / 224.0f;
        #pragma unroll
        for (int bb = 0; bb < B_; ++bb)
            G[(size_t)bb * N_ * N_ + (size_t)j * N_ + n] =
                (acc[bb] + pacc[j][bb] + bj * dinv_s[bb]) * inv;
    }
}

// ---------------------------------------------------------------------------
extern "C" void kernel_launch(void* const* d_in, const int* in_sizes, int n_in,
                              void* d_out, int out_size, void* d_ws, size_t ws_size,
                              hipStream_t stream) {
    const float* x    = (const float*)d_in[0];
    const float* W_ih = (const float*)d_in[1];
    const float* b_ih = (const float*)d_in[2];
    const float* b_hh = (const float*)d_in[3];
    const float* W_fc = (const float*)d_in[4];
    const float* b_fc = (const float*)d_in[5];

    float* G    = (float*)d_out;                        // B*N*N = 131072
    float* xhat = (float*)d_out + (size_t)B_ * N_ * N_; // B*TT*N = 229376

    float* wsum = (float*)d_ws;              // 16384
    float* bsum = wsum + N_ * H_;            // 128
    float* Hd   = bsum + N_;                 // 131072
    float* Dinv = Hd + (size_t)B_ * N_ * H_; // 1024

    k_pre<<<dim3(N_), dim3(512), 0, stream>>>(W_fc, b_fc, wsum, bsum);
    k_main<<<dim3(N_, B_), dim3(256), 0, stream>>>(x, W_ih, b_ih, b_hh,
                                                   wsum, bsum, Hd, Dinv, xhat);
    k_g<<<dim3(N_), dim3(256), 0, stream>>>(W_fc, b_fc, Hd, Dinv, G);
}

// Round 5
// 128.409 us; speedup vs baseline: 1.6465x; 1.6465x over previous
//
#include <hip/hip_runtime.h>
#include <math.h>

#define B_  8
#define N_  128
#define T_  256
#define L_  32
#define H_  128
#define TT_ 224   // T - L

typedef float f4  __attribute__((ext_vector_type(4)));
typedef float f32x4 __attribute__((ext_vector_type(4)));
typedef short bf16x8 __attribute__((ext_vector_type(8)));

__device__ __forceinline__ float fsig(float x) {
    return __builtin_amdgcn_rcpf(1.0f + __expf(-x));
}
__device__ __forceinline__ float ftanh_(float x) {
    return 1.0f - 2.0f * __builtin_amdgcn_rcpf(1.0f + __expf(2.0f * x));
}
__device__ __forceinline__ unsigned pk2bf(float a, float b) {   // RNE bf16 pack
    unsigned ua = __float_as_uint(a), ub = __float_as_uint(b);
    ua = (ua + 0x7FFFu + ((ua >> 16) & 1u)) >> 16;
    ub = (ub + 0x7FFFu + ((ub >> 16) & 1u)) >> 16;
    return ua | (ub << 16);
}

// ---------------------------------------------------------------------------
// Kernel 0: per n —
//   wsum[n,h] = sum_j W_fc[n,j,h];  bsum[n] = sum_j b_fc[n,j]
//   W3g[n]    = bf16(W_ih rows for gates i,g,o) as [384][32]  (gate f is dead)
//   bia_g[n]  = b_ih + b_hh for the same 384 rows
// ---------------------------------------------------------------------------
__global__ __launch_bounds__(512)
void k_pre(const float* __restrict__ W_fc, const float* __restrict__ b_fc,
           const float* __restrict__ W_ih, const float* __restrict__ b_ih,
           const float* __restrict__ b_hh,
           float* __restrict__ wsum, float* __restrict__ bsum,
           unsigned short* __restrict__ W3g, float* __restrict__ bia_g) {
    const int n  = blockIdx.x;
    const int h  = threadIdx.x & 127;
    const int jq = threadIdx.x >> 7;          // 0..3
    const float* W = W_fc + (size_t)n * N_ * H_ + (size_t)jq * 32 * H_;
    float s = 0.f;
    #pragma unroll 8
    for (int j = 0; j < 32; ++j) s += W[j * H_ + h];
    __shared__ float part[4][128];
    __shared__ float bp[2];
    part[jq][h] = s;

    if (threadIdx.x < 128) {
        float bv = b_fc[n * N_ + threadIdx.x];
        #pragma unroll
        for (int off = 32; off > 0; off >>= 1) bv += __shfl_down(bv, off, 64);
        if ((threadIdx.x & 63) == 0) bp[threadIdx.x >> 6] = bv;
    }
    __syncthreads();
    if (threadIdx.x < 128)
        wsum[n * H_ + h] = part[0][h] + part[1][h] + part[2][h] + part[3][h];
    if (threadIdx.x == 0) bsum[n] = bp[0] + bp[1];

    // ---- W_ih -> bf16 W3g: rows [0..127]=gi, [128..255]=gg(src+128), [256..383]=go(src+128)
    const f4* Wi = (const f4*)(W_ih + (size_t)n * 4 * H_ * L_);
    for (int i = threadIdx.x; i < 3072; i += 512) {    // 3072 f4 chunks
        const int r  = i >> 3;            // packed row 0..383
        const int c4 = i & 7;             // f4 within row
        const int sr = r + (r >= 128 ? 128 : 0);
        f4 v = Wi[sr * 8 + c4];
        unsigned2_t: ;
        unsigned p0 = pk2bf(v.x, v.y), p1 = pk2bf(v.z, v.w);
        *(uint2*)&W3g[(size_t)n * 12288 + r * 32 + c4 * 4] = make_uint2(p0, p1);
    }
    // ---- fused bias
    for (int i = threadIdx.x; i < 384; i += 512) {
        const int sr = i + (i >= 128 ? 128 : 0);
        bia_g[n * 384 + i] = b_ih[(size_t)n * 4 * H_ + sr] + b_hh[(size_t)n * 4 * H_ + sr];
    }
}

// ---------------------------------------------------------------------------
// Kernel 1: per (n,b) block, 4 waves. Gate GEMM via mfma_f32_16x16x32_bf16:
//   gates[t,g] = sum_l x[t+l] * W[g,l]   (M=224 t, N=384 g, K=32=L, one MFMA/K)
// A = Hankel(x) built per-lane from bf16 x pairs in LDS (xeo parity trick);
// B = W3 bf16 from LDS (row stride 40 -> <=2-way conflicts, 16B aligned).
// Wave w handles ht in {2w, 2w+1} (16 h-columns each); per ttile: 1 A-frag,
// 6 MFMAs (2 ht x 3 gates), activations, online Hd/X_hat reductions.
// Replaces R1-R4's scalar FMA loop that the allocator kept de-registering.
// ---------------------------------------------------------------------------
__global__ __launch_bounds__(256)
__attribute__((amdgpu_waves_per_eu(4, 4)))
void k_main(const float* __restrict__ x,
            const unsigned short* __restrict__ W3g,
            const float* __restrict__ bia_g,
            const float* __restrict__ wsum, const float* __restrict__ bsum,
            float* __restrict__ Hd, float* __restrict__ Dinv,
            float* __restrict__ xhat) {
    const int n   = blockIdx.x;
    const int b   = blockIdx.y;
    const int tid = threadIdx.x;
    const int w    = tid >> 6;    // wave 0..3
    const int lane = tid & 63;
    const int col  = lane & 15;   // MFMA m/n index
    const int quad = lane >> 4;   // MFMA k-group / row-group

    __shared__ unsigned short W3[384 * 40];   // 30720 B, stride 40 bf16
    __shared__ float xs[258];
    __shared__ unsigned xeo[2][128];          // bf16 pairs: [0]=even-start, [1]=shift-1
    __shared__ float xr[TT_];
    __shared__ float bia_s[384];
    __shared__ float ws_s[H_];
    __shared__ float xh_part[4][TT_];
    __shared__ float red[4];

    // ---- stage W3 (bf16), x, bias, wsum ----
    {
        const ushort4* src4 = (const ushort4*)(W3g + (size_t)n * 12288);
        #pragma unroll
        for (int k = 0; k < 12; ++k) {                 // 3072 ushort4 chunks
            const int i = tid + k * 256;
            const int r = i >> 3, c = (i & 7) * 4;
            *(ushort4*)&W3[r * 40 + c] = src4[i];
        }
    }
    if (tid < 256) xs[tid] = x[((size_t)b * N_ + n) * T_ + tid];
    if (tid < 2)   xs[256 + tid] = 0.f;
    if (tid < 128) ws_s[tid] = wsum[n * H_ + tid];
    for (int i = tid; i < 384; i += 256) bia_s[i] = bia_g[n * 384 + i];
    __syncthreads();
    if (tid < TT_) xr[tid] = 1.0f / xs[L_ + tid];
    if (tid < 128) {
        xeo[0][tid] = pk2bf(xs[2 * tid],     xs[2 * tid + 1]);
        xeo[1][tid] = pk2bf(xs[2 * tid + 1], xs[2 * tid + 2]);
    }
    __syncthreads();

    // ---- B-frags: 2 ht x 3 gates, register-resident (24 VGPRs) ----
    bf16x8 bfr[2][3];
    float  biaL[2][3], wshL[2];
    #pragma unroll
    for (int ht2 = 0; ht2 < 2; ++ht2) {
        const int ht = 2 * w + ht2;
        #pragma unroll
        for (int g = 0; g < 3; ++g) {
            const int row = g * 128 + ht * 16 + col;
            bfr[ht2][g]  = *(const bf16x8*)&W3[row * 40 + quad * 8];
            biaL[ht2][g] = bia_s[g * 128 + ht * 16 + col];
        }
        wshL[ht2] = ws_s[ht * 16 + col];
    }

    float hd_acc[2] = {0.f, 0.f};
    const f32x4 zero4 = {0.f, 0.f, 0.f, 0.f};

    for (int ttile = 0; ttile < 14; ++ttile) {
        // A-frag: x[s..s+7] as bf16, s = ttile*16 + col + quad*8
        const int s = ttile * 16 + col + quad * 8;
        const int p = s & 1, base = s >> 1;
        union { unsigned u[4]; bf16x8 v; } af;
        #pragma unroll
        for (int q = 0; q < 4; ++q) af.u[q] = xeo[p][base + q];

        const f4 xr4 = *(const f4*)&xr[ttile * 16 + quad * 4];
        float px[4] = {0.f, 0.f, 0.f, 0.f};

        #pragma unroll
        for (int ht2 = 0; ht2 < 2; ++ht2) {
            f32x4 ai = __builtin_amdgcn_mfma_f32_16x16x32_bf16(af.v, bfr[ht2][0], zero4, 0, 0, 0);
            f32x4 ag = __builtin_amdgcn_mfma_f32_16x16x32_bf16(af.v, bfr[ht2][1], zero4, 0, 0, 0);
            f32x4 ao = __builtin_amdgcn_mfma_f32_16x16x32_bf16(af.v, bfr[ht2][2], zero4, 0, 0, 0);
            #pragma unroll
            for (int reg = 0; reg < 4; ++reg) {
                const float gi = ai[reg] + biaL[ht2][0];
                const float gg = ag[reg] + biaL[ht2][1];
                const float go = ao[reg] + biaL[ht2][2];
                const float c  = fsig(gi) * ftanh_(gg);
                const float hh = fsig(go) * ftanh_(c);
                hd_acc[ht2] = fmaf(hh, xr4[reg], hd_acc[ht2]);
                px[reg]     = fmaf(hh, wshL[ht2], px[reg]);
            }
        }
        // X_hat partial: sum over this wave's 32 h (in-lane) then 16 n-lanes
        #pragma unroll
        for (int reg = 0; reg < 4; ++reg) {
            float pv = px[reg];
            pv += __shfl_xor(pv, 1, 64);
            pv += __shfl_xor(pv, 2, 64);
            pv += __shfl_xor(pv, 4, 64);
            pv += __shfl_xor(pv, 8, 64);
            if (col == 0) xh_part[w][ttile * 16 + quad * 4 + reg] = pv;
        }
    }

    // ---- Hd: reduce across quads, write 2x16 h per wave ----
    #pragma unroll
    for (int ht2 = 0; ht2 < 2; ++ht2) {
        float v = hd_acc[ht2];
        v += __shfl_xor(v, 16, 64);
        v += __shfl_xor(v, 32, 64);
        if (lane < 16)
            Hd[((size_t)b * N_ + n) * H_ + (2 * w + ht2) * 16 + lane] = v;
    }

    __syncthreads();
    // ---- X_hat writeout ----
    if (tid < TT_) {
        const float v = xh_part[0][tid] + xh_part[1][tid] +
                        xh_part[2][tid] + xh_part[3][tid];
        xhat[((size_t)b * TT_ + tid) * N_ + n] = v + bsum[n] + 1e-6f;
    }
    // ---- Dinv ----
    float dv = (tid < TT_) ? xr[tid] : 0.f;
    #pragma unroll
    for (int off = 32; off > 0; off >>= 1) dv += __shfl_down(dv, off, 64);
    if (lane == 0) red[w] = dv;
    __syncthreads();
    if (tid == 0) Dinv[b * N_ + n] = red[0] + red[1] + red[2] + red[3];
}

// ---------------------------------------------------------------------------
// Kernel 2: G[b,j,n] = (1/224)*(sum_h W_fc[n,j,h]*Hd[b,n,h] + b_fc[n,j]*Dinv[b,n])
// ---------------------------------------------------------------------------
__global__ __launch_bounds__(256)
void k_g(const float* __restrict__ W_fc, const float* __restrict__ b_fc,
         const float* __restrict__ Hd, const float* __restrict__ Dinv,
         float* __restrict__ G) {
    const int n = blockIdx.x;
    __shared__ f4 wrow[128 * 33];          // 67.6 KB
    __shared__ float hd_s[B_][H_];
    __shared__ float dinv_s[B_];
    __shared__ float pacc[128][B_];

    const f4* Wg = (const f4*)(W_fc + (size_t)n * N_ * H_);   // 4096 f4
    for (int i = threadIdx.x; i < 4096; i += 256) {
        const int j = i >> 5, c = i & 31;
        wrow[j * 33 + c] = Wg[i];
    }
    for (int i = threadIdx.x; i < B_ * H_; i += 256)
        hd_s[i >> 7][i & 127] = Hd[((size_t)(i >> 7) * N_ + n) * H_ + (i & 127)];
    if (threadIdx.x < B_) dinv_s[threadIdx.x] = Dinv[threadIdx.x * N_ + n];
    __syncthreads();

    const int j   = threadIdx.x & 127;
    const int hh2 = threadIdx.x >> 7;   // 0 or 1 (wave-uniform)
    float acc[B_];
    #pragma unroll
    for (int bb = 0; bb < B_; ++bb) acc[bb] = 0.f;
    #pragma unroll
    for (int q = 0; q < 16; ++q) {
        const f4 w = wrow[j * 33 + hh2 * 16 + q];
        const int hb = hh2 * 64 + q * 4;
        #pragma unroll
        for (int bb = 0; bb < B_; ++bb) {
            acc[bb] = fmaf(w[0], hd_s[bb][hb + 0],
                      fmaf(w[1], hd_s[bb][hb + 1],
                      fmaf(w[2], hd_s[bb][hb + 2],
                      fmaf(w[3], hd_s[bb][hb + 3], acc[bb]))));
        }
    }
    if (hh2 == 1) {
        #pragma unroll
        for (int bb = 0; bb < B_; ++bb) pacc[j][bb] = acc[bb];
    }
    __syncthreads();
    if (hh2 == 0) {
        const float bj  = b_fc[n * N_ + j];
        const float inv = 1.0f / 224.0f;
        #pragma unroll
        for (int bb = 0; bb < B_; ++bb)
            G[(size_t)bb * N_ * N_ + (size_t)j * N_ + n] =
                (acc[bb] + pacc[j][bb] + bj * dinv_s[bb]) * inv;
    }
}

// ---------------------------------------------------------------------------
extern "C" void kernel_launch(void* const* d_in, const int* in_sizes, int n_in,
                              void* d_out, int out_size, void* d_ws, size_t ws_size,
                              hipStream_t stream) {
    const float* x    = (const float*)d_in[0];
    const float* W_ih = (const float*)d_in[1];
    const float* b_ih = (const float*)d_in[2];
    const float* b_hh = (const float*)d_in[3];
    const float* W_fc = (const float*)d_in[4];
    const float* b_fc = (const float*)d_in[5];

    float* G    = (float*)d_out;                        // B*N*N = 131072
    float* xhat = (float*)d_out + (size_t)B_ * N_ * N_; // B*TT*N = 229376

    float* wsum = (float*)d_ws;                   // 16384
    float* bsum = wsum + N_ * H_;                 // 128
    float* Hd   = bsum + N_;                      // 131072
    float* Dinv = Hd + (size_t)B_ * N_ * H_;      // 1024
    float* bia_g = Dinv + B_ * N_;                // 49152
    unsigned short* W3g = (unsigned short*)(bia_g + N_ * 384);  // 128*12288 bf16

    k_pre<<<dim3(N_), dim3(512), 0, stream>>>(W_fc, b_fc, W_ih, b_ih, b_hh,
                                              wsum, bsum, W3g, bia_g);
    k_main<<<dim3(N_, B_), dim3(256), 0, stream>>>(x, W3g, bia_g,
                                                   wsum, bsum, Hd, Dinv, xhat);
    k_g<<<dim3(N_), dim3(256), 0, stream>>>(W_fc, b_fc, Hd, Dinv, G);
}

// Round 6
// 119.978 us; speedup vs baseline: 1.7622x; 1.0703x over previous
//
#include <hip/hip_runtime.h>
#include <math.h>

#define B_  8
#define N_  128
#define T_  256
#define L_  32
#define H_  128
#define TT_ 224   // T - L

typedef float f4    __attribute__((ext_vector_type(4)));
typedef float f32x4 __attribute__((ext_vector_type(4)));
typedef short bf16x8 __attribute__((ext_vector_type(8)));

__device__ __forceinline__ float fsig(float x) {
    return __builtin_amdgcn_rcpf(1.0f + __expf(-x));
}
__device__ __forceinline__ float ftanh_(float x) {
    return 1.0f - 2.0f * __builtin_amdgcn_rcpf(1.0f + __expf(2.0f * x));
}
__device__ __forceinline__ unsigned pk2bf(float a, float b) {   // RNE bf16 pack
    unsigned ua = __float_as_uint(a), ub = __float_as_uint(b);
    ua = (ua + 0x7FFFu + ((ua >> 16) & 1u)) >> 16;
    ub = (ub + 0x7FFFu + ((ub >> 16) & 1u)) >> 16;
    return ua | (ub << 16);
}

// ---------------------------------------------------------------------------
// Kernel 1: per (n,b) block, 4 waves. Self-contained (k_pre deleted — its
// 128-block dispatch left 3/4 of the GPU idle; all prep is now redundant
// per-block L2/L3-hit work in the prologue):
//   - W_ih rows (gates i,g,o; f is dead) -> bf16 W3 in LDS
//   - wsum[h] = sum_j W_fc[n,j,h], bsum = sum_j b_fc[n,j]
//   - fused bias b_ih+b_hh
// Main loop (unchanged from R5's 3x win): gate GEMM via mfma_f32_16x16x32_bf16,
// M=224(t) N=384(g) K=32(L); A = Hankel(x) via bf16 parity pairs in LDS;
// activations + online Hd / X_hat / Dinv reductions.
// ---------------------------------------------------------------------------
__global__ __launch_bounds__(256)
__attribute__((amdgpu_waves_per_eu(4, 4)))
void k_main(const float* __restrict__ x, const float* __restrict__ W_ih,
            const float* __restrict__ b_ih, const float* __restrict__ b_hh,
            const float* __restrict__ W_fc, const float* __restrict__ b_fc,
            float* __restrict__ Hd, float* __restrict__ Dinv,
            float* __restrict__ xhat) {
    const int n   = blockIdx.x;
    const int b   = blockIdx.y;
    const int tid = threadIdx.x;
    const int w    = tid >> 6;    // wave 0..3
    const int lane = tid & 63;
    const int col  = lane & 15;   // MFMA m/n index
    const int quad = lane >> 4;   // MFMA k-group / row-group

    __shared__ unsigned short W3[384 * 40];   // 30720 B, bf16, row stride 40
    __shared__ float xs[258];
    __shared__ unsigned xeo[2][128];          // bf16 pairs: [0]=even-start, [1]=shift-1
    __shared__ float xr[TT_];
    __shared__ float bia_s[384];
    __shared__ float ws_s[H_];
    __shared__ float xh_part[4][TT_];         // also aliased as prologue scratch
    __shared__ float red[4];
    __shared__ float bsum_s;

    float* bfv   = &xh_part[0][0];   // [128]  prologue-only alias
    float* part2 = &xh_part[1][0];   // [256]  prologue-only alias (spans xh_part[1..2])

    // ---- prologue: W_ih -> bf16 W3 (rows 0..127=gi, 128..255=gg, 256..383=go)
    {
        const f4* Wi = (const f4*)(W_ih + (size_t)n * 4 * H_ * L_);
        #pragma unroll
        for (int k = 0; k < 12; ++k) {        // 3072 f4 chunks
            const int i  = tid + k * 256;
            const int r  = i >> 3;            // packed row 0..383
            const int c4 = i & 7;
            const int sr = r + (r >= 128 ? 128 : 0);
            f4 v = Wi[sr * 8 + c4];
            unsigned p0 = pk2bf(v.x, v.y), p1 = pk2bf(v.z, v.w);
            *(uint2*)&W3[r * 40 + c4 * 4] = make_uint2(p0, p1);
        }
    }
    // ---- prologue: wsum partials (2-way j-split), bias fuse, bsum staging, x
    {
        const int h = tid & 127, jq = tid >> 7;           // jq 0..1, 64 j each
        const float* Wf = W_fc + (size_t)n * N_ * H_ + (size_t)jq * 64 * H_ + h;
        float s = 0.f;
        #pragma unroll 8
        for (int j = 0; j < 64; ++j) s += Wf[j * H_];
        part2[jq * 128 + h] = s;
    }
    for (int i = tid; i < 384; i += 256) {
        const int sr = i + (i >= 128 ? 128 : 0);
        bia_s[i] = b_ih[(size_t)n * 4 * H_ + sr] + b_hh[(size_t)n * 4 * H_ + sr];
    }
    if (tid < 128) bfv[tid] = b_fc[n * N_ + tid];
    if (tid < 256) xs[tid] = x[((size_t)b * N_ + n) * T_ + tid];
    if (tid < 2)   xs[256 + tid] = 0.f;
    __syncthreads();

    if (tid < TT_) xr[tid] = 1.0f / xs[L_ + tid];
    if (tid < 128) {
        xeo[0][tid] = pk2bf(xs[2 * tid],     xs[2 * tid + 1]);
        xeo[1][tid] = pk2bf(xs[2 * tid + 1], xs[2 * tid + 2]);
    }
    if (tid < 128) ws_s[tid] = part2[tid] + part2[128 + tid];
    if (tid < 64) {
        float t = bfv[tid] + bfv[tid + 64];
        #pragma unroll
        for (int off = 32; off > 0; off >>= 1) t += __shfl_down(t, off, 64);
        if (tid == 0) bsum_s = t;
    }
    __syncthreads();

    // ---- B-frags: 2 ht x 3 gates, register-resident (24 VGPRs) ----
    bf16x8 bfr[2][3];
    float  biaL[2][3], wshL[2];
    #pragma unroll
    for (int ht2 = 0; ht2 < 2; ++ht2) {
        const int ht = 2 * w + ht2;
        #pragma unroll
        for (int g = 0; g < 3; ++g) {
            const int row = g * 128 + ht * 16 + col;
            bfr[ht2][g]  = *(const bf16x8*)&W3[row * 40 + quad * 8];
            biaL[ht2][g] = bia_s[g * 128 + ht * 16 + col];
        }
        wshL[ht2] = ws_s[ht * 16 + col];
    }

    float hd_acc[2] = {0.f, 0.f};
    const f32x4 zero4 = {0.f, 0.f, 0.f, 0.f};

    for (int ttile = 0; ttile < 14; ++ttile) {
        // A-frag: x[s..s+7] as bf16, s = ttile*16 + col + quad*8
        const int s = ttile * 16 + col + quad * 8;
        const int p = s & 1, base = s >> 1;
        union { unsigned u[4]; bf16x8 v; } af;
        #pragma unroll
        for (int q = 0; q < 4; ++q) af.u[q] = xeo[p][base + q];

        const f4 xr4 = *(const f4*)&xr[ttile * 16 + quad * 4];
        float px[4] = {0.f, 0.f, 0.f, 0.f};

        #pragma unroll
        for (int ht2 = 0; ht2 < 2; ++ht2) {
            f32x4 ai = __builtin_amdgcn_mfma_f32_16x16x32_bf16(af.v, bfr[ht2][0], zero4, 0, 0, 0);
            f32x4 ag = __builtin_amdgcn_mfma_f32_16x16x32_bf16(af.v, bfr[ht2][1], zero4, 0, 0, 0);
            f32x4 ao = __builtin_amdgcn_mfma_f32_16x16x32_bf16(af.v, bfr[ht2][2], zero4, 0, 0, 0);
            #pragma unroll
            for (int reg = 0; reg < 4; ++reg) {
                const float gi = ai[reg] + biaL[ht2][0];
                const float gg = ag[reg] + biaL[ht2][1];
                const float go = ao[reg] + biaL[ht2][2];
                const float c  = fsig(gi) * ftanh_(gg);
                const float hh = fsig(go) * ftanh_(c);
                hd_acc[ht2] = fmaf(hh, xr4[reg], hd_acc[ht2]);
                px[reg]     = fmaf(hh, wshL[ht2], px[reg]);
            }
        }
        // X_hat partial: sum over this wave's 32 h (in-lane) then 16 n-lanes
        #pragma unroll
        for (int reg = 0; reg < 4; ++reg) {
            float pv = px[reg];
            pv += __shfl_xor(pv, 1, 64);
            pv += __shfl_xor(pv, 2, 64);
            pv += __shfl_xor(pv, 4, 64);
            pv += __shfl_xor(pv, 8, 64);
            if (col == 0) xh_part[w][ttile * 16 + quad * 4 + reg] = pv;
        }
    }

    // ---- Hd: reduce across quads, write 2x16 h per wave ----
    #pragma unroll
    for (int ht2 = 0; ht2 < 2; ++ht2) {
        float v = hd_acc[ht2];
        v += __shfl_xor(v, 16, 64);
        v += __shfl_xor(v, 32, 64);
        if (lane < 16)
            Hd[((size_t)b * N_ + n) * H_ + (2 * w + ht2) * 16 + lane] = v;
    }

    __syncthreads();
    // ---- X_hat writeout ----
    if (tid < TT_) {
        const float v = xh_part[0][tid] + xh_part[1][tid] +
                        xh_part[2][tid] + xh_part[3][tid];
        xhat[((size_t)b * TT_ + tid) * N_ + n] = v + bsum_s + 1e-6f;
    }
    // ---- Dinv ----
    float dv = (tid < TT_) ? xr[tid] : 0.f;
    #pragma unroll
    for (int off = 32; off > 0; off >>= 1) dv += __shfl_down(dv, off, 64);
    if (lane == 0) red[w] = dv;
    __syncthreads();
    if (tid == 0) Dinv[b * N_ + n] = red[0] + red[1] + red[2] + red[3];
}

// ---------------------------------------------------------------------------
// Kernel 2: G[b,j,n] = (1/224)*(sum_h W_fc[n,j,h]*Hd[b,n,h] + b_fc[n,j]*Dinv[b,n])
// R6: grid (N, 8) = 1024 blocks (R5 had 128 blocks / 67 KB LDS = 0.5 blocks/CU
// actual). Each block: 16 j-rows, 8 KB W staging, per-thread (j,col) partial
// dot over 8 h, LDS reduction over the 16 cols.
// ---------------------------------------------------------------------------
__global__ __launch_bounds__(256)
void k_g(const float* __restrict__ W_fc, const float* __restrict__ b_fc,
         const float* __restrict__ Hd, const float* __restrict__ Dinv,
         float* __restrict__ G) {
    const int n  = blockIdx.x;
    const int j0 = blockIdx.y * 16;
    const int tid = threadIdx.x;

    __shared__ float ws[16][132];       // 16 j x 128 h, padded
    __shared__ float hd_s[B_][132];     // padded
    __shared__ float dinv_s[B_];
    __shared__ float pacc[16][16][8];   // [j][col][b]

    const f4* Wg = (const f4*)(W_fc + ((size_t)n * N_ + j0) * H_);   // 512 f4
    #pragma unroll
    for (int k = 0; k < 2; ++k) {
        const int i = tid + k * 256;
        *(f4*)&ws[i >> 5][(i & 31) * 4] = Wg[i];
    }
    for (int i = tid; i < B_ * H_; i += 256)
        hd_s[i >> 7][i & 127] = Hd[((size_t)(i >> 7) * N_ + n) * H_ + (i & 127)];
    if (tid < B_) dinv_s[tid] = Dinv[tid * N_ + n];
    __syncthreads();

    const int jl  = tid >> 4;   // 0..15
    const int cl  = tid & 15;   // h-slice of 8
    float acc[B_];
    #pragma unroll
    for (int bb = 0; bb < B_; ++bb) acc[bb] = 0.f;
    #pragma unroll
    for (int q = 0; q < 2; ++q) {
        const f4 wv = *(const f4*)&ws[jl][cl * 8 + q * 4];
        const int hb = cl * 8 + q * 4;
        #pragma unroll
        for (int bb = 0; bb < B_; ++bb) {
            acc[bb] = fmaf(wv.x, hd_s[bb][hb + 0],
                      fmaf(wv.y, hd_s[bb][hb + 1],
                      fmaf(wv.z, hd_s[bb][hb + 2],
                      fmaf(wv.w, hd_s[bb][hb + 3], acc[bb]))));
        }
    }
    #pragma unroll
    for (int bb = 0; bb < B_; ++bb) pacc[jl][cl][bb] = acc[bb];
    __syncthreads();

    if (tid < 128) {
        const int j2 = tid >> 3, bb = tid & 7;
        float s = 0.f;
        #pragma unroll
        for (int c = 0; c < 16; ++c) s += pacc[j2][c][bb];
        const float bj = b_fc[n * N_ + j0 + j2];
        G[(size_t)bb * N_ * N_ + (size_t)(j0 + j2) * N_ + n] =
            (s + bj * dinv_s[bb]) * (1.0f / 224.0f);
    }
}

// ---------------------------------------------------------------------------
extern "C" void kernel_launch(void* const* d_in, const int* in_sizes, int n_in,
                              void* d_out, int out_size, void* d_ws, size_t ws_size,
                              hipStream_t stream) {
    const float* x    = (const float*)d_in[0];
    const float* W_ih = (const float*)d_in[1];
    const float* b_ih = (const float*)d_in[2];
    const float* b_hh = (const float*)d_in[3];
    const float* W_fc = (const float*)d_in[4];
    const float* b_fc = (const float*)d_in[5];

    float* G    = (float*)d_out;                        // B*N*N = 131072
    float* xhat = (float*)d_out + (size_t)B_ * N_ * N_; // B*TT*N = 229376

    float* Hd   = (float*)d_ws;                   // B*N*H = 131072
    float* Dinv = Hd + (size_t)B_ * N_ * H_;      // B*N = 1024

    k_main<<<dim3(N_, B_), dim3(256), 0, stream>>>(x, W_ih, b_ih, b_hh,
                                                   W_fc, b_fc, Hd, Dinv, xhat);
    k_g<<<dim3(N_, 8), dim3(256), 0, stream>>>(W_fc, b_fc, Hd, Dinv, G);
}

// Round 8
// 117.407 us; speedup vs baseline: 1.8008x; 1.0219x over previous
//
#include <hip/hip_runtime.h>
#include <math.h>

#define B_  8
#define N_  128
#define T_  256
#define L_  32
#define H_  128
#define TT_ 224   // T - L

typedef float f4    __attribute__((ext_vector_type(4)));
typedef float f32x4 __attribute__((ext_vector_type(4)));
typedef short bf16x8 __attribute__((ext_vector_type(8)));

__device__ __forceinline__ float fsig(float x) {
    return __builtin_amdgcn_rcpf(1.0f + __expf(-x));
}
__device__ __forceinline__ float ftanh_(float x) {
    return 1.0f - 2.0f * __builtin_amdgcn_rcpf(1.0f + __expf(2.0f * x));
}
__device__ __forceinline__ unsigned pk2bf(float a, float b) {   // RNE bf16 pack
    unsigned ua = __float_as_uint(a), ub = __float_as_uint(b);
    ua = (ua + 0x7FFFu + ((ua >> 16) & 1u)) >> 16;
    ub = (ub + 0x7FFFu + ((ub >> 16) & 1u)) >> 16;
    return ua | (ub << 16);
}

// ---------------------------------------------------------------------------
// Kernel 0, grid (N, 7) x 256:
//  y = 0..5: W_ih -> bf16 W3sw for this n, PRE-SWIZZLED into per-lane MFMA
//    B-frag order: W3sw[(n*1536 + fg*64 + lane)*8 + k], fg = ht*3 + g,
//    lane = quad*16+col, source row sr = r + (r>=128?128:0) with
//    r = g*128 + ht*16 + col, k-offset quad*8. idx = y*256+tid in [0,1536) —
//    no gid->n division (R7's 2048-vs-1536 stride bug class is gone).
//  y = 6: wsum[n,h]=sum_j W_fc[n,j,h], bsum[n]=sum_j b_fc[n,j],
//    bia[n,r]=b_ih+b_hh (packed 3-gate rows).
// ---------------------------------------------------------------------------
__global__ __launch_bounds__(256)
void k_pre(const float* __restrict__ W_ih, const float* __restrict__ W_fc,
           const float* __restrict__ b_ih, const float* __restrict__ b_hh,
           const float* __restrict__ b_fc,
           unsigned short* __restrict__ W3sw, float* __restrict__ wsum,
           float* __restrict__ bsum, float* __restrict__ bia_g) {
    const int n   = blockIdx.x;
    const int pid = blockIdx.y;   // 0..6
    const int tid = threadIdx.x;
    if (pid < 6) {
        const int idx  = pid * 256 + tid;          // 0..1535
        const int fg   = idx >> 6;                 // 0..23
        const int lane = idx & 63;
        const int col  = lane & 15, quad = lane >> 4;
        const int g    = fg % 3, ht = fg / 3;
        const int r    = g * 128 + ht * 16 + col;
        const int sr   = r + (r >= 128 ? 128 : 0);
        const f4* src = (const f4*)(W_ih + (size_t)n * 512 * L_ + sr * L_ + quad * 8);
        f4 v0 = src[0], v1 = src[1];
        uint4 out;
        out.x = pk2bf(v0.x, v0.y); out.y = pk2bf(v0.z, v0.w);
        out.z = pk2bf(v1.x, v1.y); out.w = pk2bf(v1.z, v1.w);
        *(uint4*)&W3sw[((size_t)n * 1536 + idx) * 8] = out;
    } else {
        __shared__ f4 part[8][32];
        __shared__ float bp[2];
        {   // wsum: thread (jg=tid>>5, h4=tid&31) sums 16 j
            const int h4 = tid & 31, jg = tid >> 5;
            const f4* Wf = (const f4*)(W_fc + (size_t)n * N_ * H_) + (size_t)jg * 16 * 32 + h4;
            f4 s = {0.f, 0.f, 0.f, 0.f};
            #pragma unroll
            for (int j = 0; j < 16; ++j) s += Wf[j * 32];
            part[jg][h4] = s;
        }
        if (tid < 128) {   // bsum partials
            float bv = b_fc[n * N_ + tid];
            #pragma unroll
            for (int off = 32; off > 0; off >>= 1) bv += __shfl_down(bv, off, 64);
            if ((tid & 63) == 0) bp[tid >> 6] = bv;
        }
        // bia: packed rows 0..383
        for (int i = tid; i < 384; i += 256) {
            const int sr = i + (i >= 128 ? 128 : 0);
            bia_g[n * 384 + i] = b_ih[(size_t)n * 512 + sr] + b_hh[(size_t)n * 512 + sr];
        }
        __syncthreads();
        if (tid < 32) {
            f4 s = part[0][tid];
            #pragma unroll
            for (int jg = 1; jg < 8; ++jg) s += part[jg][tid];
            *(f4*)&wsum[n * H_ + tid * 4] = s;
        }
        if (tid == 0) bsum[n] = bp[0] + bp[1];
    }
}

// ---------------------------------------------------------------------------
// Kernel 1: per (n,b) block, 4 waves. Fully fused (unchanged from R7):
//  - B-frags: 6 coalesced 16B loads from pre-swizzled W3sw (no LDS, no convert)
//  - gate GEMM via mfma_f32_16x16x32_bf16 (M=224 t, N=384 g, K=32=L),
//    A = Hankel(x) from bf16 parity pairs in LDS
//  - activations + online Hd / X_hat / Dinv reductions
//  - fused G epilogue: G[b,j,n] from LDS-resident Hd/Dinv + L2-hit W_fc
// ---------------------------------------------------------------------------
__global__ __launch_bounds__(256)
__attribute__((amdgpu_waves_per_eu(4, 4)))
void k_main(const float* __restrict__ x,
            const unsigned short* __restrict__ W3sw,
            const float* __restrict__ bia_g,
            const float* __restrict__ wsum, const float* __restrict__ bsum,
            const float* __restrict__ W_fc, const float* __restrict__ b_fc,
            float* __restrict__ G, float* __restrict__ xhat) {
    const int n   = blockIdx.x;
    const int b   = blockIdx.y;
    const int tid = threadIdx.x;
    const int w    = tid >> 6;    // wave 0..3
    const int lane = tid & 63;
    const int col  = lane & 15;   // MFMA m/n index
    const int quad = lane >> 4;   // MFMA k-group / row-group

    __shared__ float xs[258];
    __shared__ unsigned xeo[2][128];   // bf16 pairs: [0]=even-start, [1]=shift-1
    __shared__ float xr[TT_];
    __shared__ float xh_part[4][TT_];
    __shared__ float hd_loc[H_];
    __shared__ float red[4];

    // ---- B-frags: 6 coalesced 16B loads (pre-swizzled) ----
    const uint4* wsw = (const uint4*)W3sw + (size_t)n * 24 * 64 + lane;
    union { uint4 u; bf16x8 v; } bfr[2][3];
    float biaL[2][3], wshL[2];
    #pragma unroll
    for (int ht2 = 0; ht2 < 2; ++ht2) {
        const int ht = 2 * w + ht2;
        #pragma unroll
        for (int g = 0; g < 3; ++g) {
            bfr[ht2][g].u = wsw[(size_t)(ht * 3 + g) * 64];
            biaL[ht2][g]  = bia_g[n * 384 + g * 128 + ht * 16 + col];
        }
        wshL[ht2] = wsum[n * H_ + ht * 16 + col];
    }
    const float bsum_n = bsum[n];

    // ---- stage x ----
    xs[tid] = x[((size_t)b * N_ + n) * T_ + tid];
    if (tid < 2) xs[256 + tid] = 0.f;
    __syncthreads();
    if (tid < TT_) xr[tid] = 1.0f / xs[L_ + tid];
    if (tid < 128) {
        xeo[0][tid] = pk2bf(xs[2 * tid],     xs[2 * tid + 1]);
        xeo[1][tid] = pk2bf(xs[2 * tid + 1], xs[2 * tid + 2]);
    }
    __syncthreads();

    float hd_acc[2] = {0.f, 0.f};
    const f32x4 zero4 = {0.f, 0.f, 0.f, 0.f};

    for (int ttile = 0; ttile < 14; ++ttile) {
        // A-frag: x[s..s+7] as bf16, s = ttile*16 + col + quad*8
        const int s = ttile * 16 + col + quad * 8;
        const int p = s & 1, base = s >> 1;
        union { unsigned u[4]; bf16x8 v; } af;
        #pragma unroll
        for (int q = 0; q < 4; ++q) af.u[q] = xeo[p][base + q];

        const f4 xr4 = *(const f4*)&xr[ttile * 16 + quad * 4];
        float px[4] = {0.f, 0.f, 0.f, 0.f};

        #pragma unroll
        for (int ht2 = 0; ht2 < 2; ++ht2) {
            f32x4 ai = __builtin_amdgcn_mfma_f32_16x16x32_bf16(af.v, bfr[ht2][0].v, zero4, 0, 0, 0);
            f32x4 ag = __builtin_amdgcn_mfma_f32_16x16x32_bf16(af.v, bfr[ht2][1].v, zero4, 0, 0, 0);
            f32x4 ao = __builtin_amdgcn_mfma_f32_16x16x32_bf16(af.v, bfr[ht2][2].v, zero4, 0, 0, 0);
            #pragma unroll
            for (int reg = 0; reg < 4; ++reg) {
                const float gi = ai[reg] + biaL[ht2][0];
                const float gg = ag[reg] + biaL[ht2][1];
                const float go = ao[reg] + biaL[ht2][2];
                const float c  = fsig(gi) * ftanh_(gg);
                const float hh = fsig(go) * ftanh_(c);
                hd_acc[ht2] = fmaf(hh, xr4[reg], hd_acc[ht2]);
                px[reg]     = fmaf(hh, wshL[ht2], px[reg]);
            }
        }
        // X_hat partial: sum over this wave's 32 h (in-lane) then 16 n-lanes
        #pragma unroll
        for (int reg = 0; reg < 4; ++reg) {
            float pv = px[reg];
            pv += __shfl_xor(pv, 1, 64);
            pv += __shfl_xor(pv, 2, 64);
            pv += __shfl_xor(pv, 4, 64);
            pv += __shfl_xor(pv, 8, 64);
            if (col == 0) xh_part[w][ttile * 16 + quad * 4 + reg] = pv;
        }
    }

    // ---- Hd -> LDS (reduce across quads), Dinv partials ----
    #pragma unroll
    for (int ht2 = 0; ht2 < 2; ++ht2) {
        float v = hd_acc[ht2];
        v += __shfl_xor(v, 16, 64);
        v += __shfl_xor(v, 32, 64);
        if (lane < 16) hd_loc[(2 * w + ht2) * 16 + lane] = v;
    }
    {
        float dv = (tid < TT_) ? xr[tid] : 0.f;
        #pragma unroll
        for (int off = 32; off > 0; off >>= 1) dv += __shfl_down(dv, off, 64);
        if (lane == 0) red[w] = dv;
    }
    __syncthreads();

    // ---- X_hat writeout ----
    if (tid < TT_) {
        const float v = xh_part[0][tid] + xh_part[1][tid] +
                        xh_part[2][tid] + xh_part[3][tid];
        xhat[((size_t)b * TT_ + tid) * N_ + n] = v + bsum_n + 1e-6f;
    }

    // ---- fused G epilogue: thread pair (j, half) sums 64 h each ----
    {
        const float dinv = red[0] + red[1] + red[2] + red[3];
        const int j    = tid >> 1;
        const int half = tid & 1;
        const f4* Wf = (const f4*)(W_fc + ((size_t)n * N_ + j) * H_ + half * 64);
        float s = 0.f;
        #pragma unroll
        for (int q = 0; q < 16; ++q) {
            const f4 wv = Wf[q];
            const int hb = half * 64 + q * 4;
            s = fmaf(wv.x, hd_loc[hb + 0],
                fmaf(wv.y, hd_loc[hb + 1],
                fmaf(wv.z, hd_loc[hb + 2],
                fmaf(wv.w, hd_loc[hb + 3], s))));
        }
        s += __shfl_xor(s, 1, 64);
        if (half == 0) {
            const float bj = b_fc[n * N_ + j];
            G[(size_t)b * N_ * N_ + (size_t)j * N_ + n] =
                (s + bj * dinv) * (1.0f / 224.0f);
        }
    }
}

// ---------------------------------------------------------------------------
extern "C" void kernel_launch(void* const* d_in, const int* in_sizes, int n_in,
                              void* d_out, int out_size, void* d_ws, size_t ws_size,
                              hipStream_t stream) {
    const float* x    = (const float*)d_in[0];
    const float* W_ih = (const float*)d_in[1];
    const float* b_ih = (const float*)d_in[2];
    const float* b_hh = (const float*)d_in[3];
    const float* W_fc = (const float*)d_in[4];
    const float* b_fc = (const float*)d_in[5];

    float* G    = (float*)d_out;                        // B*N*N = 131072
    float* xhat = (float*)d_out + (size_t)B_ * N_ * N_; // B*TT*N = 229376

    unsigned short* W3sw = (unsigned short*)d_ws;             // 128*1536*8 bf16 = 3 MB
    float* wsum  = (float*)(W3sw + (size_t)N_ * 1536 * 8);    // 16384
    float* bsum  = wsum + N_ * H_;                            // 128
    float* bia_g = bsum + N_;                                 // 49152

    k_pre<<<dim3(N_, 7), dim3(256), 0, stream>>>(W_ih, W_fc, b_ih, b_hh, b_fc,
                                                 W3sw, wsum, bsum, bia_g);
    k_main<<<dim3(N_, B_), dim3(256), 0, stream>>>(x, W3sw, bia_g, wsum, bsum,
                                                   W_fc, b_fc, G, xhat);
}